// Round 7
// baseline (56.050 us; speedup 1.0000x reference)
//
#include <hip/hip_runtime.h>
#include <hip/hip_bf16.h>

#define NUM_Q_MAX 50000      // max valid query id (inclusive)
#define DIM_KEY 128
#define DIM_VAL 256
#define WF_COLS 384          // DIM_VAL + DIM_KEY
#define DIM_HID 512
#define MEMN    50
#define BIASC   50           // x col 50 == 1.0, WCt col 50 == b_f[h] (bias folded into GEMM)
#define KDIM    192          // folded feature: [0,50) corr, 50 bias, [64,192) embed
#define EOFF2   64
#define QTILES  782          // ceil(50001 / 64)
#define PARTN   50048
#define PP      72           // P LDS pitch (bf16 elems)

typedef __bf16 bf16x8 __attribute__((ext_vector_type(8)));
typedef float  f32x4  __attribute__((ext_vector_type(4)));
union Frag { uint4 u; bf16x8 b; };

__device__ __forceinline__ unsigned short f2b(float x){
    unsigned u = __float_as_uint(x);
    u += 0x7fffu + ((u >> 16) & 1u);     // round-to-nearest-even
    return (unsigned short)(u >> 16);
}
__device__ __forceinline__ unsigned pk2(float a, float b){
    return (unsigned)f2b(a) | ((unsigned)f2b(b) << 16);
}

// ---------------------------------------------------------------------------
// Kernel P (513 blocks x 64):
//  blocks 0..511: WCt fragment layout, k-layout: [0,50)=G=W_f[:,:256]@V.T,
//                 col50=b_f[h], (50,64)=0, [64,192)=W_f[:,256+j-64]
//      WCt[((nt*6+ks)*64 + l4*16 + l15)*8 + e] = WC[h=nt*16+l15][j=ks*32+l4*8+e]
//  block 512: Kbt fragment layout <- Kmem (rows >= 50 zero)
// ---------------------------------------------------------------------------
__global__ void __launch_bounds__(64)
prep_kernel(const float* __restrict__ Wf, const float* __restrict__ Vm,
            const float* __restrict__ Kmem, const float* __restrict__ bfv,
            unsigned short* __restrict__ WCt, unsigned short* __restrict__ Kbt){
    const int b = blockIdx.x, t = threadIdx.x;
    if (b < DIM_HID) {
        const int h = b, nt = h >> 4, l15 = h & 15;
        for (int j = t; j < KDIM; j += 64) {
            float val = 0.f;
            if (j < MEMN) {
                const float4* wr = (const float4*)(Wf + h * WF_COLS);
                const float4* vr = (const float4*)(Vm + j * DIM_VAL);
                float s = 0.f;
                for (int v = 0; v < DIM_VAL / 4; ++v) {
                    float4 a = wr[v], c = vr[v];
                    s += a.x*c.x + a.y*c.y + a.z*c.z + a.w*c.w;
                }
                val = s;
            } else if (j == BIASC) {
                val = bfv[h];
            } else if (j >= EOFF2) {
                val = Wf[h * WF_COLS + DIM_VAL + (j - EOFF2)];
            }
            const int ks = j >> 5, l4j = (j >> 3) & 3, e = j & 7;
            WCt[((nt * 6 + ks) * 64 + l4j * 16 + l15) * 8 + e] = f2b(val);
        }
    } else {
        for (int idx = t; idx < 4 * 4 * 64 * 8; idx += 64) {
            const int e = idx & 7, lane = (idx >> 3) & 63, ks = (idx >> 9) & 3, nt = idx >> 11;
            const int m = nt * 16 + (lane & 15), k = ks * 32 + (lane >> 4) * 8 + e;
            float v = (m < MEMN) ? Kmem[m * DIM_KEY + k] : 0.f;
            Kbt[idx] = f2b(v);
        }
    }
}

// ---------------------------------------------------------------------------
// Kernel A: single-wave blocks; block (qt, hg) computes for 64 queries the
// partial  part[hg][u] = sum_{h in hg*256..+255} w_p[h]*relu(WC[h]·x(u))
// (bias inside GEMM via x[50]=1). No __syncthreads anywhere.
// ---------------------------------------------------------------------------
__global__ void __launch_bounds__(64, 2)
table_kernel(const float* __restrict__ emb,
             const unsigned short* __restrict__ WCt,
             const unsigned short* __restrict__ Kbt,
             const float* __restrict__ wpv,
             float* __restrict__ part){
    __shared__ __align__(16) unsigned short P[64][PP];   // 9216 B, wave-private
    const int lane = threadIdx.x;
    const int l15  = lane & 15;
    const int l4   = lane >> 4;
    const int q0   = (blockIdx.x >> 1) * 64;
    const int hg   = blockIdx.x & 1;    // h half: [hg*256, hg*256+256)

    // ---- embed rows directly as A-fragments (rows q0+mt*16+l15, k=ks*32+l4*8+e) ----
    Frag ef[4][4];
    #pragma unroll
    for (int mt = 0; mt < 4; ++mt) {
        int u = q0 + mt * 16 + l15; if (u > NUM_Q_MAX) u = NUM_Q_MAX;
        const float4* eb = (const float4*)(emb + (long)u * DIM_KEY);
        #pragma unroll
        for (int ks = 0; ks < 4; ++ks) {
            float4 a = eb[ks * 8 + l4 * 2];
            float4 b = eb[ks * 8 + l4 * 2 + 1];
            uint4 w;
            w.x = pk2(a.x, a.y); w.y = pk2(a.z, a.w);
            w.z = pk2(b.x, b.y); w.w = pk2(b.z, b.w);
            ef[mt][ks].u = w;
        }
    }

    // ---- Kbt B-fragments (contiguous 1KB loads, L2-resident) ----
    Frag bk[4][4];
    #pragma unroll
    for (int n2 = 0; n2 < 4; ++n2)
        #pragma unroll
        for (int ks = 0; ks < 4; ++ks)
            bk[n2][ks].u = *(const uint4*)&Kbt[((n2 * 4 + ks) * 64 + lane) * 8];

    // ---- per m-tile: logits MFMA -> in-register softmax -> P to private LDS ----
    #pragma unroll
    for (int mt = 0; mt < 4; ++mt) {
        f32x4 la[4];
        #pragma unroll
        for (int n2 = 0; n2 < 4; ++n2) {
            la[n2] = (f32x4){0.f, 0.f, 0.f, 0.f};
            #pragma unroll
            for (int ks = 0; ks < 4; ++ks)
                la[n2] = __builtin_amdgcn_mfma_f32_16x16x32_bf16(ef[mt][ks].b, bk[n2][ks].b, la[n2], 0, 0, 0);
        }
        // C layout: row(query) = mt*16 + l4*4 + r, col(mem slot) = n2*16 + l15
        float mx[4] = {-1e30f, -1e30f, -1e30f, -1e30f};
        #pragma unroll
        for (int n2 = 0; n2 < 4; ++n2) {
            const bool ok = (n2 * 16 + l15) < MEMN;
            #pragma unroll
            for (int r = 0; r < 4; ++r)
                if (ok) mx[r] = fmaxf(mx[r], la[n2][r]);
        }
        #pragma unroll
        for (int off = 1; off < 16; off <<= 1)
            #pragma unroll
            for (int r = 0; r < 4; ++r)
                mx[r] = fmaxf(mx[r], __shfl_xor(mx[r], off, 64));
        float pv[4][4], sm[4] = {0.f, 0.f, 0.f, 0.f};
        #pragma unroll
        for (int n2 = 0; n2 < 4; ++n2) {
            const bool ok = (n2 * 16 + l15) < MEMN;
            #pragma unroll
            for (int r = 0; r < 4; ++r) {
                float v = ok ? __expf(la[n2][r] - mx[r]) : 0.f;
                pv[n2][r] = v; sm[r] += v;
            }
        }
        #pragma unroll
        for (int off = 1; off < 16; off <<= 1)
            #pragma unroll
            for (int r = 0; r < 4; ++r)
                sm[r] += __shfl_xor(sm[r], off, 64);
        float iv[4];
        #pragma unroll
        for (int r = 0; r < 4; ++r) iv[r] = 1.f / sm[r];
        #pragma unroll
        for (int n2 = 0; n2 < 4; ++n2) {
            const int col = n2 * 16 + l15;
            #pragma unroll
            for (int r = 0; r < 4; ++r) {
                float outv = (col < MEMN) ? pv[n2][r] * iv[r]
                                          : (col == BIASC ? 1.0f : 0.f);
                P[mt * 16 + l4 * 4 + r][col] = f2b(outv);
            }
        }
    }

    asm volatile("s_waitcnt lgkmcnt(0)" ::: "memory");
    __builtin_amdgcn_sched_barrier(0);

    // ---- read P back as A-fragments (k = 0..63 region, incl. bias col) ----
    Frag pa[4][2];
    #pragma unroll
    for (int mt = 0; mt < 4; ++mt)
        #pragma unroll
        for (int k2 = 0; k2 < 2; ++k2)
            pa[mt][k2].u = *(const uint4*)&P[mt * 16 + l15][k2 * 32 + l4 * 8];

    // ---- preload w_p for this wave's 16 h-tiles into registers ----
    float wpr[16];
    #pragma unroll
    for (int nt = 0; nt < 16; ++nt)
        wpr[nt] = wpv[hg * 256 + nt * 16 + l15];

    // ---- GEMM over 16 h-tiles, 3-buffer prefetch at distance 2 ----
    Frag bw[3][6];
    #pragma unroll
    for (int p = 0; p < 2; ++p)
        #pragma unroll
        for (int ks = 0; ks < 6; ++ks)
            bw[p][ks].u = *(const uint4*)&WCt[(((hg * 16 + p) * 6 + ks) * 64 + lane) * 8];

    float psum[4][4];
    #pragma unroll
    for (int mt = 0; mt < 4; ++mt)
        #pragma unroll
        for (int r = 0; r < 4; ++r) psum[mt][r] = 0.f;

    #pragma unroll
    for (int nt = 0; nt < 16; ++nt) {
        if (nt + 2 < 16) {
            #pragma unroll
            for (int ks = 0; ks < 6; ++ks)
                bw[(nt + 2) % 3][ks].u =
                    *(const uint4*)&WCt[(((hg * 16 + nt + 2) * 6 + ks) * 64 + lane) * 8];
        }
        f32x4 acc[4];
        #pragma unroll
        for (int mt = 0; mt < 4; ++mt) acc[mt] = (f32x4){0.f, 0.f, 0.f, 0.f};
        #pragma unroll
        for (int k2 = 0; k2 < 2; ++k2)
            #pragma unroll
            for (int mt = 0; mt < 4; ++mt)
                acc[mt] = __builtin_amdgcn_mfma_f32_16x16x32_bf16(pa[mt][k2].b, bw[nt % 3][k2].b, acc[mt], 0, 0, 0);
        #pragma unroll
        for (int ke = 0; ke < 4; ++ke)
            #pragma unroll
            for (int mt = 0; mt < 4; ++mt)
                acc[mt] = __builtin_amdgcn_mfma_f32_16x16x32_bf16(ef[mt][ke].b, bw[nt % 3][2 + ke].b, acc[mt], 0, 0, 0);
        #pragma unroll
        for (int mt = 0; mt < 4; ++mt)
            #pragma unroll
            for (int r = 0; r < 4; ++r)
                psum[mt][r] += wpr[nt] * fmaxf(acc[mt][r], 0.f);   // bias already in acc
    }

    // ---- reduce across the 16 h-lanes (l15) ----
    #pragma unroll
    for (int off = 1; off < 16; off <<= 1)
        #pragma unroll
        for (int mt = 0; mt < 4; ++mt)
            #pragma unroll
            for (int r = 0; r < 4; ++r)
                psum[mt][r] += __shfl_xor(psum[mt][r], off, 64);

    if (l15 == 0) {
        #pragma unroll
        for (int mt = 0; mt < 4; ++mt)
            #pragma unroll
            for (int r = 0; r < 4; ++r) {
                const int u = q0 + mt * 16 + l4 * 4 + r;
                if (u <= NUM_Q_MAX) part[hg * PARTN + u] = psum[mt][r];
            }
    }
}

// ---------------------------------------------------------------------------
// Kernel B: out[i] = sigmoid(part0[q[i]] + part1[q[i]] + b_p)
// ---------------------------------------------------------------------------
__global__ void gather_kernel(const int* __restrict__ q, const float* __restrict__ part,
                              const float* __restrict__ bpv, float* __restrict__ out, int n){
    int i = blockIdx.x * 256 + threadIdx.x;
    if (i < n) {
        const int u = q[i];
        const float s = part[u] + part[PARTN + u] + bpv[0];
        out[i] = 1.f / (1.f + __expf(-s));
    }
}

extern "C" void kernel_launch(void* const* d_in, const int* in_sizes, int n_in,
                              void* d_out, int out_size, void* d_ws, size_t ws_size,
                              hipStream_t stream) {
    const int*   q    = (const int*)  d_in[0];
    // d_in[1] = a (unused by forward math)
    const float* Kmem = (const float*)d_in[2];
    const float* Vmem = (const float*)d_in[3];
    const float* emb  = (const float*)d_in[4];
    // d_in[5..8] = W_erase/b_erase/W_add/b_add (unused)
    const float* Wf   = (const float*)d_in[9];
    const float* bf   = (const float*)d_in[10];
    const float* wp   = (const float*)d_in[11];
    const float* bp   = (const float*)d_in[12];
    float* out = (float*)d_out;

    unsigned short* WCt  = (unsigned short*)d_ws;                          // 196608 B
    unsigned short* Kbt  = (unsigned short*)((char*)d_ws + 196608);        //  16384 B
    float*          part = (float*)((char*)d_ws + 196608 + 16384);         // 2*50048*4 B

    prep_kernel<<<DIM_HID + 1, 64, 0, stream>>>(Wf, Vmem, Kmem, bf, WCt, Kbt);

    table_kernel<<<QTILES * 2, 64, 0, stream>>>(emb, WCt, Kbt, wp, part);

    gather_kernel<<<(out_size + 255) / 256, 256, 0, stream>>>(q, part, bp, out, out_size);
}

// Round 8
// 52.240 us; speedup vs baseline: 1.0729x; 1.0729x over previous
//
#include <hip/hip_runtime.h>
#include <hip/hip_bf16.h>

#define NUM_Q_MAX 50000      // max valid query id (inclusive)
#define DIM_KEY 128
#define DIM_VAL 256
#define WF_COLS 384          // DIM_VAL + DIM_KEY
#define DIM_HID 512
#define MEMN    50
#define KDIM    192          // folded feature: [0,50) corr, [56,184) embed, rest 0
#define EOFF    56
#define PITCH   200          // LDS row pitch in bf16 elems
#define QB      64

typedef __bf16 bf16x8 __attribute__((ext_vector_type(8)));
typedef float  f32x4  __attribute__((ext_vector_type(4)));
union Frag { uint4 u; bf16x8 b; };

__device__ __forceinline__ float blo(unsigned u){ return __uint_as_float(u << 16); }
__device__ __forceinline__ float bhi(unsigned u){ return __uint_as_float(u & 0xffff0000u); }
__device__ __forceinline__ unsigned short f2b(float x){
    unsigned u = __float_as_uint(x);
    u += 0x7fffu + ((u >> 16) & 1u);     // round-to-nearest-even
    return (unsigned short)(u >> 16);
}
__device__ __forceinline__ unsigned pk2(float a, float b){
    return (unsigned)f2b(a) | ((unsigned)f2b(b) << 16);
}

// ---------------------------------------------------------------------------
// Kernel P (513 blocks x 64):
//  blocks 0..511: WCt fragment-layout  WCt[nt=h>>4][ks][lane=l4*16+(h&15)][e] =
//      (j<50)? dot(W_f[h,0:256],V[j,:]) : (56<=j<184)? W_f[h,256+j-56] : 0,  j=ks*32+l4*8+e
//  block 512: Kbt[nt][ks][lane][e] <- Kmem (bf16 fragment layout, rows>=50 zero)
// ---------------------------------------------------------------------------
__global__ void __launch_bounds__(64)
prep_kernel(const float* __restrict__ Wf, const float* __restrict__ Vm,
            const float* __restrict__ Kmem,
            unsigned short* __restrict__ WCt, unsigned short* __restrict__ Kbt){
    const int b = blockIdx.x, t = threadIdx.x;
    if (b < DIM_HID) {
        const int h = b, nt = h >> 4, l15 = h & 15;
        for (int j = t; j < KDIM; j += 64) {
            float val = 0.f;
            if (j < MEMN) {
                const float4* wr = (const float4*)(Wf + h * WF_COLS);
                const float4* vr = (const float4*)(Vm + j * DIM_VAL);
                float s = 0.f;
                for (int v = 0; v < DIM_VAL / 4; ++v) {
                    float4 a = wr[v], c = vr[v];
                    s += a.x*c.x + a.y*c.y + a.z*c.z + a.w*c.w;
                }
                val = s;
            } else if (j >= EOFF && j < EOFF + DIM_KEY) {
                val = Wf[h * WF_COLS + DIM_VAL + (j - EOFF)];
            }
            const int ks = j >> 5, l4 = (j >> 3) & 3, e = j & 7;
            WCt[((nt * 6 + ks) * 64 + l4 * 16 + l15) * 8 + e] = f2b(val);
        }
    } else {
        for (int idx = t; idx < 4 * 4 * 64 * 8; idx += 64) {
            const int e = idx & 7, lane = (idx >> 3) & 63, ks = (idx >> 9) & 3, nt = idx >> 11;
            const int m = nt * 16 + (lane & 15), k = ks * 32 + (lane >> 4) * 8 + e;
            float v = (m < MEMN) ? Kmem[m * DIM_KEY + k] : 0.f;
            Kbt[idx] = f2b(v);
        }
    }
}

// ---------------------------------------------------------------------------
// Kernel A: p[u] = sigmoid( sum_h w_p[h]*relu( WC[h]·x(u) + b_f[h] ) + b_p )
//           x(u) = [softmax(K·e(u)) ‖ e(u)], e(u)=embed_table[u]
// ---------------------------------------------------------------------------
__global__ void __launch_bounds__(256, 4)
table_kernel(const float* __restrict__ emb,
             const unsigned short* __restrict__ WCt,
             const unsigned short* __restrict__ Kbt,
             const float* __restrict__ bfv, const float* __restrict__ wpv,
             const float* __restrict__ bpv, float* __restrict__ table){
    __shared__ __align__(16) unsigned short xf[QB * PITCH];
    __shared__ float2 bwl[DIM_HID];
    __shared__ float red[QB][2];
    const int tid  = threadIdx.x;
    const int u0   = blockIdx.x * QB;
    const int lane = tid & 63;
    const int wv   = tid >> 6;          // wave 0..3
    const int l15  = lane & 15;
    const int l4   = lane >> 4;
    const int mg   = wv & 1;            // phase-2 m-group (q rows mg*32..+31)
    const int hg   = wv >> 1;           // phase-2 h-group (h hg*256..+255)

    // ---- fragment-shaped embed load: thread owns row wv*16+l15, cols ks*32+l4*8 ----
    int u = u0 + wv * 16 + l15; if (u > NUM_Q_MAX) u = NUM_Q_MAX;
    const float4* ebase = (const float4*)(emb + (long)u * DIM_KEY);
    float4 s0[4], s1[4];
    #pragma unroll
    for (int ks = 0; ks < 4; ++ks) {
        s0[ks] = ebase[ks * 8 + l4 * 2];
        s1[ks] = ebase[ks * 8 + l4 * 2 + 1];
    }
    // bias/w_p preload (4 coalesced loads)
    float bf0 = bfv[tid], wp0 = wpv[tid];
    float bf1 = bfv[tid + 256], wp1 = wpv[tid + 256];
    // Kbt fragment loads (contiguous 1KB per instr)
    Frag bk[4][4];
    #pragma unroll
    for (int nt2 = 0; nt2 < 4; ++nt2)
        #pragma unroll
        for (int ks = 0; ks < 4; ++ks)
            bk[nt2][ks].u = *(const uint4*)&Kbt[((nt2 * 4 + ks) * 64 + lane) * 8];

    // ---- convert to ef fragments; same data staged to LDS ----
    Frag ef[4];
    #pragma unroll
    for (int ks = 0; ks < 4; ++ks) {
        uint4 w;
        w.x = pk2(s0[ks].x, s0[ks].y); w.y = pk2(s0[ks].z, s0[ks].w);
        w.z = pk2(s1[ks].x, s1[ks].y); w.w = pk2(s1[ks].z, s1[ks].w);
        ef[ks].u = w;
        *(uint4*)&xf[(wv * 16 + l15) * PITCH + EOFF + ks * 32 + l4 * 8] = w;
    }
    if (tid < QB) {
        uint4 z = {0u, 0u, 0u, 0u};
        *(uint4*)&xf[tid * PITCH + EOFF + DIM_KEY] = z;   // cols 184..191
    }
    bwl[tid]       = make_float2(bf0, wp0);
    bwl[tid + 256] = make_float2(bf1, wp1);

    // ---- logits via MFMA (no barrier needed: A from regs, B from Kbt) ----
    #pragma unroll
    for (int nt2 = 0; nt2 < 4; ++nt2) {
        f32x4 acc = {0.f, 0.f, 0.f, 0.f};
        #pragma unroll
        for (int ks = 0; ks < 4; ++ks)
            acc = __builtin_amdgcn_mfma_f32_16x16x32_bf16(ef[ks].b, bk[nt2][ks].b, acc, 0, 0, 0);
        const int mcol = nt2 * 16 + l15;
        if (mcol < MEMN) {
            #pragma unroll
            for (int r = 0; r < 4; ++r)
                xf[(wv * 16 + l4 * 4 + r) * PITCH + mcol] = f2b(acc[r]);
        }
    }

    // ---- prefetch WC nt=0 (fragment layout, contiguous) ----
    Frag bwA[6], bwB[6];
    #pragma unroll
    for (int ks = 0; ks < 6; ++ks)
        bwA[ks].u = *(const uint4*)&WCt[(((hg * 16) * 6 + ks) * 64 + lane) * 8];

    __syncthreads();   // staging + logits visible

    // ---- af embed fragments (cols >=64), concurrent with softmax ----
    Frag af[2][6];
    #pragma unroll
    for (int mt = 0; mt < 2; ++mt)
        #pragma unroll
        for (int ks = 2; ks < 6; ++ks)
            af[mt][ks].u = *(const uint4*)&xf[(mg*32 + mt*16 + l15) * PITCH + ks*32 + l4*8];

    // ---- wave-parallel softmax, 4 threads per row (writes zeros to cols 50-55) ----
    {
        const int r = tid >> 2, g = tid & 3;
        unsigned short* rowp = &xf[r * PITCH];
        uint4 v0 = *(const uint4*)&rowp[g * 16];
        uint4 v1 = {0u, 0u, 0u, 0u};
        if (g < 3) v1 = *(const uint4*)&rowp[g * 16 + 8];
        float va[16];
        va[0]=blo(v0.x); va[1]=bhi(v0.x); va[2]=blo(v0.y);  va[3]=bhi(v0.y);
        va[4]=blo(v0.z); va[5]=bhi(v0.z); va[6]=blo(v0.w);  va[7]=bhi(v0.w);
        va[8]=blo(v1.x); va[9]=bhi(v1.x); va[10]=blo(v1.y); va[11]=bhi(v1.y);
        va[12]=blo(v1.z); va[13]=bhi(v1.z); va[14]=blo(v1.w); va[15]=bhi(v1.w);
        const int c0 = g * 16;
        float mx = -1e30f;
        #pragma unroll
        for (int e = 0; e < 16; ++e) if (c0 + e < MEMN) mx = fmaxf(mx, va[e]);
        mx = fmaxf(mx, __shfl_xor(mx, 1, 64));
        mx = fmaxf(mx, __shfl_xor(mx, 2, 64));
        float sum = 0.f;
        #pragma unroll
        for (int e = 0; e < 16; ++e) {
            float ev = (c0 + e < MEMN) ? __expf(va[e] - mx) : 0.f;
            va[e] = ev; sum += ev;
        }
        sum += __shfl_xor(sum, 1, 64);
        sum += __shfl_xor(sum, 2, 64);
        const float inv = 1.f / sum;
        uint4 w0, w1;
        w0.x = pk2(va[0]*inv,  va[1]*inv);  w0.y = pk2(va[2]*inv,  va[3]*inv);
        w0.z = pk2(va[4]*inv,  va[5]*inv);  w0.w = pk2(va[6]*inv,  va[7]*inv);
        *(uint4*)&rowp[g * 16] = w0;
        if (g < 3) {
            w1.x = pk2(va[8]*inv,  va[9]*inv);  w1.y = pk2(va[10]*inv, va[11]*inv);
            w1.z = pk2(va[12]*inv, va[13]*inv); w1.w = pk2(va[14]*inv, va[15]*inv);
            *(uint4*)&rowp[g * 16 + 8] = w1;
        }
    }
    __syncthreads();   // softmax visible

    // ---- af corr fragments (cols 0..63) ----
    #pragma unroll
    for (int mt = 0; mt < 2; ++mt)
        #pragma unroll
        for (int ks = 0; ks < 2; ++ks)
            af[mt][ks].u = *(const uint4*)&xf[(mg*32 + mt*16 + l15) * PITCH + ks*32 + l4*8];

    // ---- main GEMM loop: 1-deep WCt prefetch, bias from LDS (no vmcnt drain) ----
    const int kseq[6] = {2, 3, 4, 5, 0, 1};   // softmax-dependent frags last
    float psum[2][4] = {{0.f,0.f,0.f,0.f},{0.f,0.f,0.f,0.f}};
    #pragma unroll
    for (int nt = 0; nt < 16; ++nt) {
        Frag* cur = (nt & 1) ? bwB : bwA;
        Frag* nxt = (nt & 1) ? bwA : bwB;
        if (nt < 15) {
            const int g1 = hg * 16 + nt + 1;
            #pragma unroll
            for (int ks = 0; ks < 6; ++ks)
                nxt[ks].u = *(const uint4*)&WCt[((g1 * 6 + ks) * 64 + lane) * 8];
        }
        const float2 bw2 = bwl[hg * 256 + nt * 16 + l15];
        f32x4 acc[2] = {{0.f,0.f,0.f,0.f},{0.f,0.f,0.f,0.f}};
        #pragma unroll
        for (int ksi = 0; ksi < 6; ++ksi) {
            const int ks = kseq[ksi];
            #pragma unroll
            for (int mt = 0; mt < 2; ++mt)
                acc[mt] = __builtin_amdgcn_mfma_f32_16x16x32_bf16(af[mt][ks].b, cur[ks].b, acc[mt], 0, 0, 0);
        }
        #pragma unroll
        for (int mt = 0; mt < 2; ++mt)
            #pragma unroll
            for (int r = 0; r < 4; ++r)
                psum[mt][r] += bw2.y * fmaxf(acc[mt][r] + bw2.x, 0.f);
    }

    // ---- reduce across the 16 h-lanes of this wave ----
    #pragma unroll
    for (int off = 1; off < 16; off <<= 1)
        #pragma unroll
        for (int mt = 0; mt < 2; ++mt)
            #pragma unroll
            for (int r = 0; r < 4; ++r)
                psum[mt][r] += __shfl_xor(psum[mt][r], off, 64);

    if (l15 == 0) {
        #pragma unroll
        for (int mt = 0; mt < 2; ++mt)
            #pragma unroll
            for (int r = 0; r < 4; ++r)
                red[mg*32 + mt*16 + l4*4 + r][hg] = psum[mt][r];
    }
    __syncthreads();

    if (tid < QB) {
        float s = red[tid][0] + red[tid][1] + bpv[0];
        float p = 1.f / (1.f + __expf(-s));
        int uo = u0 + tid;
        if (uo <= NUM_Q_MAX) table[uo] = p;
    }
}

// ---------------------------------------------------------------------------
// Kernel B: out[i] = table[q[i]]
// ---------------------------------------------------------------------------
__global__ void gather_kernel(const int* __restrict__ q, const float* __restrict__ table,
                              float* __restrict__ out, int n){
    int i = blockIdx.x * 256 + threadIdx.x;
    if (i < n) out[i] = table[q[i]];
}

extern "C" void kernel_launch(void* const* d_in, const int* in_sizes, int n_in,
                              void* d_out, int out_size, void* d_ws, size_t ws_size,
                              hipStream_t stream) {
    const int*   q    = (const int*)  d_in[0];
    // d_in[1] = a (unused by forward math)
    const float* Kmem = (const float*)d_in[2];
    const float* Vmem = (const float*)d_in[3];
    const float* emb  = (const float*)d_in[4];
    // d_in[5..8] = W_erase/b_erase/W_add/b_add (unused)
    const float* Wf   = (const float*)d_in[9];
    const float* bf   = (const float*)d_in[10];
    const float* wp   = (const float*)d_in[11];
    const float* bp   = (const float*)d_in[12];
    float* out = (float*)d_out;

    unsigned short* WCt   = (unsigned short*)d_ws;                         // 512*192*2 = 196608 B
    unsigned short* Kbt   = (unsigned short*)((char*)d_ws + 196608);       // 8192*2    =  16384 B
    float*          table = (float*)((char*)d_ws + 196608 + 16384);        // 50048*4 B

    prep_kernel<<<DIM_HID + 1, 64, 0, stream>>>(Wf, Vmem, Kmem, WCt, Kbt);

    int nblk = (NUM_Q_MAX + 1 + QB - 1) / QB;   // 782
    table_kernel<<<nblk, 256, 0, stream>>>(emb, WCt, Kbt, bf, wp, bp, table);

    gather_kernel<<<(out_size + 255) / 256, 256, 0, stream>>>(q, table, out, out_size);
}

// Round 9
// 49.231 us; speedup vs baseline: 1.1385x; 1.0611x over previous
//
#include <hip/hip_runtime.h>
#include <hip/hip_bf16.h>

#define NUM_Q_MAX 50000      // max valid query id (inclusive)
#define DIM_KEY 128
#define DIM_VAL 256
#define WF_COLS 384          // DIM_VAL + DIM_KEY
#define DIM_HID 512
#define MEMN    50
#define KDIM    192          // folded feature: [0,50) corr, [56,184) embed, rest 0
#define EOFF    56
#define PITCH   200          // LDS row pitch in bf16 elems
#define QB      64

typedef __bf16 bf16x8 __attribute__((ext_vector_type(8)));
typedef float  f32x4  __attribute__((ext_vector_type(4)));
union Frag { uint4 u; bf16x8 b; };

__device__ __forceinline__ float blo(unsigned u){ return __uint_as_float(u << 16); }
__device__ __forceinline__ float bhi(unsigned u){ return __uint_as_float(u & 0xffff0000u); }
__device__ __forceinline__ unsigned short f2b(float x){
    unsigned u = __float_as_uint(x);
    u += 0x7fffu + ((u >> 16) & 1u);     // round-to-nearest-even
    return (unsigned short)(u >> 16);
}
__device__ __forceinline__ unsigned pk2(float a, float b){
    return (unsigned)f2b(a) | ((unsigned)f2b(b) << 16);
}

// ---------------------------------------------------------------------------
// Kernel P (513 blocks x 64):
//  blocks 0..511: WCt fragment-layout  WCt[nt=h>>4][ks][lane=l4*16+(h&15)][e] =
//      (j<50)? dot(W_f[h,0:256],V[j,:]) : (56<=j<184)? W_f[h,256+j-56] : 0,  j=ks*32+l4*8+e
//  block 512: Kbt[nt][ks][lane][e] <- Kmem (bf16 fragment layout, rows>=50 zero)
// ---------------------------------------------------------------------------
__global__ void __launch_bounds__(64)
prep_kernel(const float* __restrict__ Wf, const float* __restrict__ Vm,
            const float* __restrict__ Kmem,
            unsigned short* __restrict__ WCt, unsigned short* __restrict__ Kbt){
    const int b = blockIdx.x, t = threadIdx.x;
    if (b < DIM_HID) {
        const int h = b, nt = h >> 4, l15 = h & 15;
        for (int j = t; j < KDIM; j += 64) {
            float val = 0.f;
            if (j < MEMN) {
                const float4* wr = (const float4*)(Wf + h * WF_COLS);
                const float4* vr = (const float4*)(Vm + j * DIM_VAL);
                float s = 0.f;
                for (int v = 0; v < DIM_VAL / 4; ++v) {
                    float4 a = wr[v], c = vr[v];
                    s += a.x*c.x + a.y*c.y + a.z*c.z + a.w*c.w;
                }
                val = s;
            } else if (j >= EOFF && j < EOFF + DIM_KEY) {
                val = Wf[h * WF_COLS + DIM_VAL + (j - EOFF)];
            }
            const int ks = j >> 5, l4 = (j >> 3) & 3, e = j & 7;
            WCt[((nt * 6 + ks) * 64 + l4 * 16 + l15) * 8 + e] = f2b(val);
        }
    } else {
        for (int idx = t; idx < 4 * 4 * 64 * 8; idx += 64) {
            const int e = idx & 7, lane = (idx >> 3) & 63, ks = (idx >> 9) & 3, nt = idx >> 11;
            const int m = nt * 16 + (lane & 15), k = ks * 32 + (lane >> 4) * 8 + e;
            float v = (m < MEMN) ? Kmem[m * DIM_KEY + k] : 0.f;
            Kbt[idx] = f2b(v);
        }
    }
}

// ---------------------------------------------------------------------------
// Kernel A: p[u] = sigmoid( sum_h w_p[h]*relu( WC[h]·x(u) + b_f[h] ) + b_p )
//           x(u) = [softmax(K·e(u)) ‖ e(u)], e(u)=embed_table[u]
//           R9: per-block staggered nt order (bph) to break the L2 convoy.
// ---------------------------------------------------------------------------
__global__ void __launch_bounds__(256, 4)
table_kernel(const float* __restrict__ emb,
             const unsigned short* __restrict__ WCt,
             const unsigned short* __restrict__ Kbt,
             const float* __restrict__ bfv, const float* __restrict__ wpv,
             const float* __restrict__ bpv, float* __restrict__ table){
    __shared__ __align__(16) unsigned short xf[QB * PITCH];
    __shared__ float2 bwl[DIM_HID];
    __shared__ float red[QB][2];
    const int tid  = threadIdx.x;
    const int u0   = blockIdx.x * QB;
    const int bph  = blockIdx.x & 15;   // per-block tile-order stagger
    const int lane = tid & 63;
    const int wv   = tid >> 6;          // wave 0..3
    const int l15  = lane & 15;
    const int l4   = lane >> 4;
    const int mg   = wv & 1;            // phase-2 m-group (q rows mg*32..+31)
    const int hg   = wv >> 1;           // phase-2 h-group (h hg*256..+255)

    // ---- fragment-shaped embed load: thread owns row wv*16+l15, cols ks*32+l4*8 ----
    int u = u0 + wv * 16 + l15; if (u > NUM_Q_MAX) u = NUM_Q_MAX;
    const float4* ebase = (const float4*)(emb + (long)u * DIM_KEY);
    float4 s0[4], s1[4];
    #pragma unroll
    for (int ks = 0; ks < 4; ++ks) {
        s0[ks] = ebase[ks * 8 + l4 * 2];
        s1[ks] = ebase[ks * 8 + l4 * 2 + 1];
    }
    // bias/w_p preload (4 coalesced loads)
    float bf0 = bfv[tid], wp0 = wpv[tid];
    float bf1 = bfv[tid + 256], wp1 = wpv[tid + 256];
    // Kbt fragment loads (contiguous 1KB per instr)
    Frag bk[4][4];
    #pragma unroll
    for (int nt2 = 0; nt2 < 4; ++nt2)
        #pragma unroll
        for (int ks = 0; ks < 4; ++ks)
            bk[nt2][ks].u = *(const uint4*)&Kbt[((nt2 * 4 + ks) * 64 + lane) * 8];

    // ---- convert to ef fragments; same data staged to LDS ----
    Frag ef[4];
    #pragma unroll
    for (int ks = 0; ks < 4; ++ks) {
        uint4 w;
        w.x = pk2(s0[ks].x, s0[ks].y); w.y = pk2(s0[ks].z, s0[ks].w);
        w.z = pk2(s1[ks].x, s1[ks].y); w.w = pk2(s1[ks].z, s1[ks].w);
        ef[ks].u = w;
        *(uint4*)&xf[(wv * 16 + l15) * PITCH + EOFF + ks * 32 + l4 * 8] = w;
    }
    if (tid < QB) {
        uint4 z = {0u, 0u, 0u, 0u};
        *(uint4*)&xf[tid * PITCH + EOFF + DIM_KEY] = z;   // cols 184..191
    }
    bwl[tid]       = make_float2(bf0, wp0);
    bwl[tid + 256] = make_float2(bf1, wp1);

    // ---- logits via MFMA (no barrier needed: A from regs, B from Kbt) ----
    #pragma unroll
    for (int nt2 = 0; nt2 < 4; ++nt2) {
        f32x4 acc = {0.f, 0.f, 0.f, 0.f};
        #pragma unroll
        for (int ks = 0; ks < 4; ++ks)
            acc = __builtin_amdgcn_mfma_f32_16x16x32_bf16(ef[ks].b, bk[nt2][ks].b, acc, 0, 0, 0);
        const int mcol = nt2 * 16 + l15;
        if (mcol < MEMN) {
            #pragma unroll
            for (int r = 0; r < 4; ++r)
                xf[(wv * 16 + l4 * 4 + r) * PITCH + mcol] = f2b(acc[r]);
        }
    }

    // ---- prefetch WC tile bph (fragment layout, contiguous) ----
    Frag bwA[6], bwB[6];
    #pragma unroll
    for (int ks = 0; ks < 6; ++ks)
        bwA[ks].u = *(const uint4*)&WCt[(((hg * 16 + bph) * 6 + ks) * 64 + lane) * 8];

    __syncthreads();   // staging + logits visible

    // ---- af embed fragments (cols >=64), concurrent with softmax ----
    Frag af[2][6];
    #pragma unroll
    for (int mt = 0; mt < 2; ++mt)
        #pragma unroll
        for (int ks = 2; ks < 6; ++ks)
            af[mt][ks].u = *(const uint4*)&xf[(mg*32 + mt*16 + l15) * PITCH + ks*32 + l4*8];

    // ---- wave-parallel softmax, 4 threads per row (writes zeros to cols 50-55) ----
    {
        const int r = tid >> 2, g = tid & 3;
        unsigned short* rowp = &xf[r * PITCH];
        uint4 v0 = *(const uint4*)&rowp[g * 16];
        uint4 v1 = {0u, 0u, 0u, 0u};
        if (g < 3) v1 = *(const uint4*)&rowp[g * 16 + 8];
        float va[16];
        va[0]=blo(v0.x); va[1]=bhi(v0.x); va[2]=blo(v0.y);  va[3]=bhi(v0.y);
        va[4]=blo(v0.z); va[5]=bhi(v0.z); va[6]=blo(v0.w);  va[7]=bhi(v0.w);
        va[8]=blo(v1.x); va[9]=bhi(v1.x); va[10]=blo(v1.y); va[11]=bhi(v1.y);
        va[12]=blo(v1.z); va[13]=bhi(v1.z); va[14]=blo(v1.w); va[15]=bhi(v1.w);
        const int c0 = g * 16;
        float mx = -1e30f;
        #pragma unroll
        for (int e = 0; e < 16; ++e) if (c0 + e < MEMN) mx = fmaxf(mx, va[e]);
        mx = fmaxf(mx, __shfl_xor(mx, 1, 64));
        mx = fmaxf(mx, __shfl_xor(mx, 2, 64));
        float sum = 0.f;
        #pragma unroll
        for (int e = 0; e < 16; ++e) {
            float ev = (c0 + e < MEMN) ? __expf(va[e] - mx) : 0.f;
            va[e] = ev; sum += ev;
        }
        sum += __shfl_xor(sum, 1, 64);
        sum += __shfl_xor(sum, 2, 64);
        const float inv = 1.f / sum;
        uint4 w0, w1;
        w0.x = pk2(va[0]*inv,  va[1]*inv);  w0.y = pk2(va[2]*inv,  va[3]*inv);
        w0.z = pk2(va[4]*inv,  va[5]*inv);  w0.w = pk2(va[6]*inv,  va[7]*inv);
        *(uint4*)&rowp[g * 16] = w0;
        if (g < 3) {
            w1.x = pk2(va[8]*inv,  va[9]*inv);  w1.y = pk2(va[10]*inv, va[11]*inv);
            w1.z = pk2(va[12]*inv, va[13]*inv); w1.w = pk2(va[14]*inv, va[15]*inv);
            *(uint4*)&rowp[g * 16 + 8] = w1;
        }
    }
    __syncthreads();   // softmax visible

    // ---- af corr fragments (cols 0..63) ----
    #pragma unroll
    for (int mt = 0; mt < 2; ++mt)
        #pragma unroll
        for (int ks = 0; ks < 2; ++ks)
            af[mt][ks].u = *(const uint4*)&xf[(mg*32 + mt*16 + l15) * PITCH + ks*32 + l4*8];

    // ---- main GEMM loop: staggered nt order, 1-deep WCt prefetch, bias from LDS ----
    const int kseq[6] = {2, 3, 4, 5, 0, 1};   // softmax-dependent frags last
    float psum[2][4] = {{0.f,0.f,0.f,0.f},{0.f,0.f,0.f,0.f}};
    #pragma unroll
    for (int nti = 0; nti < 16; ++nti) {
        const int nt = (nti + bph) & 15;           // real tile index (stagger)
        Frag* cur = (nti & 1) ? bwB : bwA;
        Frag* nxt = (nti & 1) ? bwA : bwB;
        if (nti < 15) {
            const int g1 = hg * 16 + ((nti + 1 + bph) & 15);
            #pragma unroll
            for (int ks = 0; ks < 6; ++ks)
                nxt[ks].u = *(const uint4*)&WCt[((g1 * 6 + ks) * 64 + lane) * 8];
        }
        const float2 bw2 = bwl[hg * 256 + nt * 16 + l15];
        f32x4 acc[2] = {{0.f,0.f,0.f,0.f},{0.f,0.f,0.f,0.f}};
        #pragma unroll
        for (int ksi = 0; ksi < 6; ++ksi) {
            const int ks = kseq[ksi];
            #pragma unroll
            for (int mt = 0; mt < 2; ++mt)
                acc[mt] = __builtin_amdgcn_mfma_f32_16x16x32_bf16(af[mt][ks].b, cur[ks].b, acc[mt], 0, 0, 0);
        }
        #pragma unroll
        for (int mt = 0; mt < 2; ++mt)
            #pragma unroll
            for (int r = 0; r < 4; ++r)
                psum[mt][r] += bw2.y * fmaxf(acc[mt][r] + bw2.x, 0.f);
    }

    // ---- reduce across the 16 h-lanes of this wave ----
    #pragma unroll
    for (int off = 1; off < 16; off <<= 1)
        #pragma unroll
        for (int mt = 0; mt < 2; ++mt)
            #pragma unroll
            for (int r = 0; r < 4; ++r)
                psum[mt][r] += __shfl_xor(psum[mt][r], off, 64);

    if (l15 == 0) {
        #pragma unroll
        for (int mt = 0; mt < 2; ++mt)
            #pragma unroll
            for (int r = 0; r < 4; ++r)
                red[mg*32 + mt*16 + l4*4 + r][hg] = psum[mt][r];
    }
    __syncthreads();

    if (tid < QB) {
        float s = red[tid][0] + red[tid][1] + bpv[0];
        float p = 1.f / (1.f + __expf(-s));
        int uo = u0 + tid;
        if (uo <= NUM_Q_MAX) table[uo] = p;
    }
}

// ---------------------------------------------------------------------------
// Kernel B: out[i] = table[q[i]]
// ---------------------------------------------------------------------------
__global__ void gather_kernel(const int* __restrict__ q, const float* __restrict__ table,
                              float* __restrict__ out, int n){
    int i = blockIdx.x * 256 + threadIdx.x;
    if (i < n) out[i] = table[q[i]];
}

extern "C" void kernel_launch(void* const* d_in, const int* in_sizes, int n_in,
                              void* d_out, int out_size, void* d_ws, size_t ws_size,
                              hipStream_t stream) {
    const int*   q    = (const int*)  d_in[0];
    // d_in[1] = a (unused by forward math)
    const float* Kmem = (const float*)d_in[2];
    const float* Vmem = (const float*)d_in[3];
    const float* emb  = (const float*)d_in[4];
    // d_in[5..8] = W_erase/b_erase/W_add/b_add (unused)
    const float* Wf   = (const float*)d_in[9];
    const float* bf   = (const float*)d_in[10];
    const float* wp   = (const float*)d_in[11];
    const float* bp   = (const float*)d_in[12];
    float* out = (float*)d_out;

    unsigned short* WCt   = (unsigned short*)d_ws;                         // 512*192*2 = 196608 B
    unsigned short* Kbt   = (unsigned short*)((char*)d_ws + 196608);       // 8192*2    =  16384 B
    float*          table = (float*)((char*)d_ws + 196608 + 16384);        // 50048*4 B

    prep_kernel<<<DIM_HID + 1, 64, 0, stream>>>(Wf, Vmem, Kmem, WCt, Kbt);

    int nblk = (NUM_Q_MAX + 1 + QB - 1) / QB;   // 782
    table_kernel<<<nblk, 256, 0, stream>>>(emb, WCt, Kbt, bf, wp, bp, table);

    gather_kernel<<<(out_size + 255) / 256, 256, 0, stream>>>(q, table, out, out_size);
}

// Round 10
// 48.459 us; speedup vs baseline: 1.1567x; 1.0159x over previous
//
#include <hip/hip_runtime.h>
#include <hip/hip_bf16.h>

#define NUM_Q_MAX 50000      // max valid query id (inclusive)
#define DIM_KEY 128
#define DIM_VAL 256
#define WF_COLS 384          // DIM_VAL + DIM_KEY
#define DIM_HID 512
#define MEMN    50
#define KDIM    192          // folded feature: [0,50) corr, [56,184) embed, rest 0
#define EOFF    56
#define PITCH   200          // LDS row pitch in bf16 elems
#define QB      64

typedef __bf16 bf16x8 __attribute__((ext_vector_type(8)));
typedef float  f32x4  __attribute__((ext_vector_type(4)));
union Frag { uint4 u; bf16x8 b; };

__device__ __forceinline__ float blo(unsigned u){ return __uint_as_float(u << 16); }
__device__ __forceinline__ float bhi(unsigned u){ return __uint_as_float(u & 0xffff0000u); }
__device__ __forceinline__ unsigned short f2b(float x){
    unsigned u = __float_as_uint(x);
    u += 0x7fffu + ((u >> 16) & 1u);     // round-to-nearest-even
    return (unsigned short)(u >> 16);
}
__device__ __forceinline__ unsigned pk2(float a, float b){
    return (unsigned)f2b(a) | ((unsigned)f2b(b) << 16);
}

// ---------------------------------------------------------------------------
// Kernel P (513 blocks x 64):
//  blocks 0..511: WCt fragment-layout  WCt[nt=h>>4][ks][lane=l4*16+(h&15)][e] =
//      (j<50)? dot(W_f[h,0:256],V[j,:]) : (56<=j<184)? W_f[h,256+j-56] : 0,  j=ks*32+l4*8+e
//  block 512: Kbt[nt][ks][lane][e] <- Kmem (bf16 fragment layout, rows>=50 zero)
// ---------------------------------------------------------------------------
__global__ void __launch_bounds__(64)
prep_kernel(const float* __restrict__ Wf, const float* __restrict__ Vm,
            const float* __restrict__ Kmem,
            unsigned short* __restrict__ WCt, unsigned short* __restrict__ Kbt){
    const int b = blockIdx.x, t = threadIdx.x;
    if (b < DIM_HID) {
        const int h = b, nt = h >> 4, l15 = h & 15;
        for (int j = t; j < KDIM; j += 64) {
            float val = 0.f;
            if (j < MEMN) {
                const float4* wr = (const float4*)(Wf + h * WF_COLS);
                const float4* vr = (const float4*)(Vm + j * DIM_VAL);
                float s = 0.f;
                for (int v = 0; v < DIM_VAL / 4; ++v) {
                    float4 a = wr[v], c = vr[v];
                    s += a.x*c.x + a.y*c.y + a.z*c.z + a.w*c.w;
                }
                val = s;
            } else if (j >= EOFF && j < EOFF + DIM_KEY) {
                val = Wf[h * WF_COLS + DIM_VAL + (j - EOFF)];
            }
            const int ks = j >> 5, l4 = (j >> 3) & 3, e = j & 7;
            WCt[((nt * 6 + ks) * 64 + l4 * 16 + l15) * 8 + e] = f2b(val);
        }
    } else {
        for (int idx = t; idx < 4 * 4 * 64 * 8; idx += 64) {
            const int e = idx & 7, lane = (idx >> 3) & 63, ks = (idx >> 9) & 3, nt = idx >> 11;
            const int m = nt * 16 + (lane & 15), k = ks * 32 + (lane >> 4) * 8 + e;
            float v = (m < MEMN) ? Kmem[m * DIM_KEY + k] : 0.f;
            Kbt[idx] = f2b(v);
        }
    }
}

// ---------------------------------------------------------------------------
// Kernel A: p[u] = sigmoid( sum_h w_p[h]*relu( WC[h]·x(u) + b_f[h] ) + b_p )
//           x(u) = [softmax(K·e(u)) ‖ e(u)], e(u)=embed_table[u]
//   R10: wave wv owns ALL 4 m-tiles x its own 8-nt quarter (h in [wv*128,+128)).
//        WCt traffic per block halves (no duplicate hg loads); 8 GEMM iters;
//        distance-2 prefetch (3-slot ring); bph stagger kept (mod 8).
// ---------------------------------------------------------------------------
__global__ void __launch_bounds__(256, 2)
table_kernel(const float* __restrict__ emb,
             const unsigned short* __restrict__ WCt,
             const unsigned short* __restrict__ Kbt,
             const float* __restrict__ bfv, const float* __restrict__ wpv,
             const float* __restrict__ bpv, float* __restrict__ table){
    __shared__ __align__(16) unsigned short xf[QB * PITCH];
    __shared__ float2 bwl[DIM_HID];
    __shared__ float red[QB][4];
    const int tid  = threadIdx.x;
    const int u0   = blockIdx.x * QB;
    const int bph  = blockIdx.x & 7;    // per-block tile-order stagger
    const int lane = tid & 63;
    const int wv   = tid >> 6;          // wave 0..3
    const int l15  = lane & 15;
    const int l4   = lane >> 4;
    const int wv8  = wv * 8;            // this wave's first nt tile (h = wv*128)

    // ---- fragment-shaped embed load: thread owns row wv*16+l15, cols ks*32+l4*8 ----
    int u = u0 + wv * 16 + l15; if (u > NUM_Q_MAX) u = NUM_Q_MAX;
    const float4* ebase = (const float4*)(emb + (long)u * DIM_KEY);
    float4 s0[4], s1[4];
    #pragma unroll
    for (int ks = 0; ks < 4; ++ks) {
        s0[ks] = ebase[ks * 8 + l4 * 2];
        s1[ks] = ebase[ks * 8 + l4 * 2 + 1];
    }
    // bias/w_p preload (4 coalesced loads)
    float bf0 = bfv[tid], wp0 = wpv[tid];
    float bf1 = bfv[tid + 256], wp1 = wpv[tid + 256];
    // Kbt fragment loads (contiguous 1KB per instr)
    Frag bk[4][4];
    #pragma unroll
    for (int nt2 = 0; nt2 < 4; ++nt2)
        #pragma unroll
        for (int ks = 0; ks < 4; ++ks)
            bk[nt2][ks].u = *(const uint4*)&Kbt[((nt2 * 4 + ks) * 64 + lane) * 8];

    // ---- convert to ef fragments; same data staged to LDS ----
    Frag ef[4];
    #pragma unroll
    for (int ks = 0; ks < 4; ++ks) {
        uint4 w;
        w.x = pk2(s0[ks].x, s0[ks].y); w.y = pk2(s0[ks].z, s0[ks].w);
        w.z = pk2(s1[ks].x, s1[ks].y); w.w = pk2(s1[ks].z, s1[ks].w);
        ef[ks].u = w;
        *(uint4*)&xf[(wv * 16 + l15) * PITCH + EOFF + ks * 32 + l4 * 8] = w;
    }
    if (tid < QB) {
        uint4 z = {0u, 0u, 0u, 0u};
        *(uint4*)&xf[tid * PITCH + EOFF + DIM_KEY] = z;   // cols 184..191
    }
    bwl[tid]       = make_float2(bf0, wp0);
    bwl[tid + 256] = make_float2(bf1, wp1);

    // ---- logits via MFMA (no barrier needed: A from regs, B from Kbt) ----
    #pragma unroll
    for (int nt2 = 0; nt2 < 4; ++nt2) {
        f32x4 acc = {0.f, 0.f, 0.f, 0.f};
        #pragma unroll
        for (int ks = 0; ks < 4; ++ks)
            acc = __builtin_amdgcn_mfma_f32_16x16x32_bf16(ef[ks].b, bk[nt2][ks].b, acc, 0, 0, 0);
        const int mcol = nt2 * 16 + l15;
        if (mcol < MEMN) {
            #pragma unroll
            for (int r = 0; r < 4; ++r)
                xf[(wv * 16 + l4 * 4 + r) * PITCH + mcol] = f2b(acc[r]);
        }
    }

    // ---- prefetch WCt tiles nti=0,1 of this wave's quarter (3-slot ring) ----
    Frag bw[3][6];
    {
        const int g0 = wv8 + (bph & 7);
        const int g1 = wv8 + ((1 + bph) & 7);
        #pragma unroll
        for (int ks = 0; ks < 6; ++ks)
            bw[0][ks].u = *(const uint4*)&WCt[((g0 * 6 + ks) * 64 + lane) * 8];
        #pragma unroll
        for (int ks = 0; ks < 6; ++ks)
            bw[1][ks].u = *(const uint4*)&WCt[((g1 * 6 + ks) * 64 + lane) * 8];
    }

    __syncthreads();   // staging + logits visible

    // ---- af embed fragments for ALL 4 m-tiles (cols >=64), concurrent w/ softmax ----
    Frag af[4][6];
    #pragma unroll
    for (int mt = 0; mt < 4; ++mt)
        #pragma unroll
        for (int ks = 2; ks < 6; ++ks)
            af[mt][ks].u = *(const uint4*)&xf[(mt*16 + l15) * PITCH + ks*32 + l4*8];

    // ---- wave-parallel softmax, 4 threads per row (writes zeros to cols 50-55) ----
    {
        const int r = tid >> 2, g = tid & 3;
        unsigned short* rowp = &xf[r * PITCH];
        uint4 v0 = *(const uint4*)&rowp[g * 16];
        uint4 v1 = {0u, 0u, 0u, 0u};
        if (g < 3) v1 = *(const uint4*)&rowp[g * 16 + 8];
        float va[16];
        va[0]=blo(v0.x); va[1]=bhi(v0.x); va[2]=blo(v0.y);  va[3]=bhi(v0.y);
        va[4]=blo(v0.z); va[5]=bhi(v0.z); va[6]=blo(v0.w);  va[7]=bhi(v0.w);
        va[8]=blo(v1.x); va[9]=bhi(v1.x); va[10]=blo(v1.y); va[11]=bhi(v1.y);
        va[12]=blo(v1.z); va[13]=bhi(v1.z); va[14]=blo(v1.w); va[15]=bhi(v1.w);
        const int c0 = g * 16;
        float mx = -1e30f;
        #pragma unroll
        for (int e = 0; e < 16; ++e) if (c0 + e < MEMN) mx = fmaxf(mx, va[e]);
        mx = fmaxf(mx, __shfl_xor(mx, 1, 64));
        mx = fmaxf(mx, __shfl_xor(mx, 2, 64));
        float sum = 0.f;
        #pragma unroll
        for (int e = 0; e < 16; ++e) {
            float ev = (c0 + e < MEMN) ? __expf(va[e] - mx) : 0.f;
            va[e] = ev; sum += ev;
        }
        sum += __shfl_xor(sum, 1, 64);
        sum += __shfl_xor(sum, 2, 64);
        const float inv = 1.f / sum;
        uint4 w0, w1;
        w0.x = pk2(va[0]*inv,  va[1]*inv);  w0.y = pk2(va[2]*inv,  va[3]*inv);
        w0.z = pk2(va[4]*inv,  va[5]*inv);  w0.w = pk2(va[6]*inv,  va[7]*inv);
        *(uint4*)&rowp[g * 16] = w0;
        if (g < 3) {
            w1.x = pk2(va[8]*inv,  va[9]*inv);  w1.y = pk2(va[10]*inv, va[11]*inv);
            w1.z = pk2(va[12]*inv, va[13]*inv); w1.w = pk2(va[14]*inv, va[15]*inv);
            *(uint4*)&rowp[g * 16 + 8] = w1;
        }
    }
    __syncthreads();   // softmax visible

    // ---- af corr fragments (cols 0..63) for all 4 m-tiles ----
    #pragma unroll
    for (int mt = 0; mt < 4; ++mt)
        #pragma unroll
        for (int ks = 0; ks < 2; ++ks)
            af[mt][ks].u = *(const uint4*)&xf[(mt*16 + l15) * PITCH + ks*32 + l4*8];

    // ---- main GEMM: 8 iters over this wave's nt quarter, distance-2 prefetch ----
    const int kseq[6] = {2, 3, 4, 5, 0, 1};   // softmax-dependent frags last
    float psum[4][4];
    #pragma unroll
    for (int mt = 0; mt < 4; ++mt)
        #pragma unroll
        for (int r = 0; r < 4; ++r) psum[mt][r] = 0.f;

    #pragma unroll
    for (int nti = 0; nti < 8; ++nti) {
        const int nt = (nti + bph) & 7;       // staggered tile within quarter
        const int g  = wv8 + nt;              // global h-tile id
        if (nti < 6) {
            const int gp = wv8 + ((nti + 2 + bph) & 7);
            #pragma unroll
            for (int ks = 0; ks < 6; ++ks)
                bw[(nti + 2) % 3][ks].u = *(const uint4*)&WCt[((gp * 6 + ks) * 64 + lane) * 8];
        }
        const float2 bw2 = bwl[g * 16 + l15];
        f32x4 acc[4];
        #pragma unroll
        for (int mt = 0; mt < 4; ++mt) acc[mt] = (f32x4){0.f, 0.f, 0.f, 0.f};
        #pragma unroll
        for (int ksi = 0; ksi < 6; ++ksi) {
            const int ks = kseq[ksi];
            #pragma unroll
            for (int mt = 0; mt < 4; ++mt)
                acc[mt] = __builtin_amdgcn_mfma_f32_16x16x32_bf16(af[mt][ks].b, bw[nti % 3][ks].b, acc[mt], 0, 0, 0);
        }
        #pragma unroll
        for (int mt = 0; mt < 4; ++mt)
            #pragma unroll
            for (int r = 0; r < 4; ++r)
                psum[mt][r] += bw2.y * fmaxf(acc[mt][r] + bw2.x, 0.f);
    }

    // ---- reduce across the 16 h-lanes (l15) of this wave ----
    #pragma unroll
    for (int off = 1; off < 16; off <<= 1)
        #pragma unroll
        for (int mt = 0; mt < 4; ++mt)
            #pragma unroll
            for (int r = 0; r < 4; ++r)
                psum[mt][r] += __shfl_xor(psum[mt][r], off, 64);

    if (l15 == 0) {
        #pragma unroll
        for (int mt = 0; mt < 4; ++mt)
            #pragma unroll
            for (int r = 0; r < 4; ++r)
                red[mt*16 + l4*4 + r][wv] = psum[mt][r];
    }
    __syncthreads();

    if (tid < QB) {
        float s = red[tid][0] + red[tid][1] + red[tid][2] + red[tid][3] + bpv[0];
        float p = 1.f / (1.f + __expf(-s));
        int uo = u0 + tid;
        if (uo <= NUM_Q_MAX) table[uo] = p;
    }
}

// ---------------------------------------------------------------------------
// Kernel B: out[i] = table[q[i]]
// ---------------------------------------------------------------------------
__global__ void gather_kernel(const int* __restrict__ q, const float* __restrict__ table,
                              float* __restrict__ out, int n){
    int i = blockIdx.x * 256 + threadIdx.x;
    if (i < n) out[i] = table[q[i]];
}

extern "C" void kernel_launch(void* const* d_in, const int* in_sizes, int n_in,
                              void* d_out, int out_size, void* d_ws, size_t ws_size,
                              hipStream_t stream) {
    const int*   q    = (const int*)  d_in[0];
    // d_in[1] = a (unused by forward math)
    const float* Kmem = (const float*)d_in[2];
    const float* Vmem = (const float*)d_in[3];
    const float* emb  = (const float*)d_in[4];
    // d_in[5..8] = W_erase/b_erase/W_add/b_add (unused)
    const float* Wf   = (const float*)d_in[9];
    const float* bf   = (const float*)d_in[10];
    const float* wp   = (const float*)d_in[11];
    const float* bp   = (const float*)d_in[12];
    float* out = (float*)d_out;

    unsigned short* WCt   = (unsigned short*)d_ws;                         // 512*192*2 = 196608 B
    unsigned short* Kbt   = (unsigned short*)((char*)d_ws + 196608);       // 8192*2    =  16384 B
    float*          table = (float*)((char*)d_ws + 196608 + 16384);        // 50048*4 B

    prep_kernel<<<DIM_HID + 1, 64, 0, stream>>>(Wf, Vmem, Kmem, WCt, Kbt);

    int nblk = (NUM_Q_MAX + 1 + QB - 1) / QB;   // 782
    table_kernel<<<nblk, 256, 0, stream>>>(emb, WCt, Kbt, bf, wp, bp, table);

    gather_kernel<<<(out_size + 255) / 256, 256, 0, stream>>>(q, table, out, out_size);
}